// Round 4
// baseline (473.166 us; speedup 1.0000x reference)
//
#include <hip/hip_runtime.h>

#define TABLE_SIZE 4096
#define BLOCK 256

// clang ext_vector type so __builtin_nontemporal_store accepts it.
typedef float f32x4 __attribute__((ext_vector_type(4)));

__device__ __forceinline__ f32x4 secgelu4(f32x4 v, const float* __restrict__ t)
{
    f32x4 r;
    #pragma unroll
    for (int k = 0; k < 4; ++k) {
        float xv = v[k];
        // X = round-half-even(x * 2^16): rintf in RN mode == np.round
        float X = rintf(xv * 65536.0f);
        // y = floor(X / 64): exact (X integral, /64 is an exponent shift)
        float y = floorf(X * 0.015625f);
        bool  d = (y >= 0.0f);                        // -0.0f >= 0 true (matches ref)
        float a = fminf(fabsf(y), (float)(TABLE_SIZE - 1));
        r[k] = (d ? xv : 0.0f) - t[(int)a];
    }
    return r;
}

__global__ __launch_bounds__(BLOCK) void secgelu_kernel(
    const float* __restrict__ x, const float* __restrict__ table,
    float* __restrict__ out, int n4, int n)
{
    __shared__ float lds_table[TABLE_SIZE];
    // Stage the 16 KB table into LDS (coalesced, 16 iters of 256 threads).
    for (int i = threadIdx.x; i < TABLE_SIZE; i += BLOCK)
        lds_table[i] = table[i];
    __syncthreads();

    const f32x4* __restrict__ x4 = (const f32x4*)x;
    f32x4* __restrict__ o4 = (f32x4*)out;

    const int stride = gridDim.x * BLOCK;
    int i0 = blockIdx.x * BLOCK + threadIdx.x;

    // Software pipeline, depth 2, tile = 4 float4s/thread.
    //
    // CRITICAL ORDERING: next tile's loads are issued BEFORE this tile's
    // stores. vmcnt decrements in issue order, so with order
    // [loads(i+1), stores(i)] the wait that consumes loads(i+1) next
    // iteration (vmcnt(4)) does NOT wait for stores(i) to be acked —
    // store retirement overlaps the next tile's load latency + compute.
    // (r3's [stores(i), loads(i+1)] order made every load-wait also wait
    // on the previous stores' HBM acks -> 1.4 TB/s. r2's conditional
    // prefetch added a branch-merge drain -> worse.)
    //
    // The prefetch is UNCONDITIONAL and branchless: on the last iteration
    // the prefetch address clamps back to the current tile (in-bounds,
    // result discarded). No divergent branch, no waitcnt merge point.
    bool have = (i0 + 3 * stride < n4);
    f32x4 a0, a1, a2, a3;
    if (have) {
        a0 = x4[i0];
        a1 = x4[i0 + stride];
        a2 = x4[i0 + 2 * stride];
        a3 = x4[i0 + 3 * stride];
    }
    while (have) {
        int i1 = i0 + 4 * stride;
        bool more = (i1 + 3 * stride < n4);
        int p = more ? i1 : i0;          // branchless clamp (v_cndmask)

        // ---- prefetch next tile (issued first!) ----
        f32x4 b0 = x4[p];
        f32x4 b1 = x4[p + stride];
        f32x4 b2 = x4[p + 2 * stride];
        f32x4 b3 = x4[p + 3 * stride];

        // ---- compute current tile ----
        f32x4 r0 = secgelu4(a0, lds_table);
        f32x4 r1 = secgelu4(a1, lds_table);
        f32x4 r2 = secgelu4(a2, lds_table);
        f32x4 r3 = secgelu4(a3, lds_table);

        // ---- store current tile (nontemporal: 268 MB written once,
        //      zero reuse — keep the write stream out of L2/L3 so the
        //      input's L3 residency keeps serving ~half the reads) ----
        __builtin_nontemporal_store(r0, &o4[i0]);
        __builtin_nontemporal_store(r1, &o4[i0 + stride]);
        __builtin_nontemporal_store(r2, &o4[i0 + 2 * stride]);
        __builtin_nontemporal_store(r3, &o4[i0 + 3 * stride]);

        a0 = b0; a1 = b1; a2 = b2; a3 = b3;
        i0 = i1;
        have = more;
    }

    // Remainder (< 4 strided tiles left; dead at this shape — n4 = 32*stride
    // exactly — but correct in general).
    for (; i0 < n4; i0 += stride) {
        f32x4 v = x4[i0];
        __builtin_nontemporal_store(secgelu4(v, lds_table), &o4[i0]);
    }

    // Tail (n not divisible by 4) — dead here, kept for safety.
    int t0 = n4 * 4 + (int)(blockIdx.x * BLOCK + threadIdx.x);
    if (blockIdx.x == 0 && t0 < n) {
        float xv = x[t0];
        float X = rintf(xv * 65536.0f);
        float y = floorf(X * 0.015625f);
        bool  d = (y >= 0.0f);
        float a = fminf(fabsf(y), (float)(TABLE_SIZE - 1));
        out[t0] = (d ? xv : 0.0f) - lds_table[(int)a];
    }
}

extern "C" void kernel_launch(void* const* d_in, const int* in_sizes, int n_in,
                              void* d_out, int out_size, void* d_ws, size_t ws_size,
                              hipStream_t stream) {
    const float* x     = (const float*)d_in[0];
    const float* table = (const float*)d_in[1];
    float* out = (float*)d_out;
    int n  = in_sizes[0];
    int n4 = n / 4;

    // 2048 blocks = 8 blocks/CU x 256 CU -> 32 waves/CU (HW cap; LDS at
    // 16 KB/block allows 10 blocks/CU, VGPRs are not the limit). Each
    // thread handles exactly 32 float4s = 8 pipelined tiles of 4.
    int blocks = 2048;
    secgelu_kernel<<<blocks, BLOCK, 0, stream>>>(x, table, out, n4, n);
}

// Round 5
// 447.555 us; speedup vs baseline: 1.0572x; 1.0572x over previous
//
#include <hip/hip_runtime.h>

#define TABLE_SIZE 4096
#define BLOCK 512   // 8 waves/block: amortizes the 16 KB LDS table over 2x
                    // more waves. r2 counters showed OccupancyPercent=53.8
                    // with 256-thr blocks (LDS capped blocks/CU at ~4-5, not
                    // the expected 8). 1024 blocks x 512 thr = 4 blocks/CU
                    // x 8 waves = 32 waves/CU (HW cap) at 64 KB LDS/CU.

// clang ext_vector type so __builtin_nontemporal_store accepts it.
typedef float f32x4 __attribute__((ext_vector_type(4)));

__device__ __forceinline__ f32x4 secgelu4(f32x4 v, const float* __restrict__ t)
{
    f32x4 r;
    #pragma unroll
    for (int k = 0; k < 4; ++k) {
        float xv = v[k];
        // X = round-half-even(x * 2^16): rintf in RN mode == np.round
        float X = rintf(xv * 65536.0f);
        // y = floor(X / 64): exact (X integral, /64 is an exponent shift)
        float y = floorf(X * 0.015625f);
        bool  d = (y >= 0.0f);                        // -0.0f >= 0 true (matches ref)
        float a = fminf(fabsf(y), (float)(TABLE_SIZE - 1));
        r[k] = (d ? xv : 0.0f) - t[(int)a];
    }
    return r;
}

__global__ __launch_bounds__(BLOCK) void secgelu_kernel(
    const float* __restrict__ x, const float* __restrict__ table,
    float* __restrict__ out, int n4, int n)
{
    __shared__ float lds_table[TABLE_SIZE];
    // Stage the 16 KB table into LDS: 1024 float4s, 2 per thread, coalesced.
    {
        const f32x4* __restrict__ t4 = (const f32x4*)table;
        f32x4* __restrict__ l4 = (f32x4*)lds_table;
        #pragma unroll
        for (int i = threadIdx.x; i < TABLE_SIZE / 4; i += BLOCK)
            l4[i] = t4[i];
    }
    __syncthreads();

    const f32x4* __restrict__ x4 = (const f32x4*)x;
    f32x4* __restrict__ o4 = (f32x4*)out;

    const int stride = gridDim.x * BLOCK;
    int idx = blockIdx.x * BLOCK + threadIdx.x;

    // Simple grid-stride loop, 2x unroll — the r0/r1 structure that measured
    // best (~153 us). r2-r4's deeper hand-pipelines all regressed: hipcc
    // re-schedules the body itself; don't fight it. The lever this round is
    // occupancy (block geometry), not the schedule.
    for (; idx + stride < n4; idx += 2 * stride) {
        f32x4 v0 = x4[idx];
        f32x4 v1 = x4[idx + stride];
        f32x4 r0 = secgelu4(v0, lds_table);
        f32x4 r1 = secgelu4(v1, lds_table);
        // NT stores: 268 MB written once, zero reuse — keep the write stream
        // from churning L2/L3 (L3 residency serves ~half the input reads).
        __builtin_nontemporal_store(r0, &o4[idx]);
        __builtin_nontemporal_store(r1, &o4[idx + stride]);
    }
    for (; idx < n4; idx += stride) {
        f32x4 v = x4[idx];
        __builtin_nontemporal_store(secgelu4(v, lds_table), &o4[idx]);
    }

    // Tail (n not divisible by 4) — dead at this shape, kept for safety.
    int t0 = n4 * 4 + (int)(blockIdx.x * BLOCK + threadIdx.x);
    if (blockIdx.x == 0 && t0 < n) {
        float xv = x[t0];
        float X = rintf(xv * 65536.0f);
        float y = floorf(X * 0.015625f);
        bool  d = (y >= 0.0f);
        float a = fminf(fabsf(y), (float)(TABLE_SIZE - 1));
        out[t0] = (d ? xv : 0.0f) - lds_table[(int)a];
    }
}

extern "C" void kernel_launch(void* const* d_in, const int* in_sizes, int n_in,
                              void* d_out, int out_size, void* d_ws, size_t ws_size,
                              hipStream_t stream) {
    const float* x     = (const float*)d_in[0];
    const float* table = (const float*)d_in[1];
    float* out = (float*)d_out;
    int n  = in_sizes[0];
    int n4 = n / 4;

    // 1024 blocks x 512 threads = 524,288 threads; 4 blocks/CU x 8 waves
    // = 32 waves/CU. Each thread handles exactly 32 float4s (16 unroll-2
    // iterations, zero remainder at this shape).
    int blocks = 1024;
    secgelu_kernel<<<blocks, BLOCK, 0, stream>>>(x, table, out, n4, n);
}